// Round 1
// baseline (177.384 us; speedup 1.0000x reference)
//
#include <hip/hip_runtime.h>
#include <hip/hip_bf16.h>

#define B_ 4
#define T_ 4096
#define C_ 1024
#define D_ 128

typedef __attribute__((ext_vector_type(8))) short short8;
typedef __attribute__((ext_vector_type(4))) float f32x4;
typedef __attribute__((ext_vector_type(4))) unsigned short ushort4v;

static __device__ __forceinline__ unsigned short f2b(float f) {
    __hip_bfloat16 h = __float2bfloat16(f);
    return __builtin_bit_cast(unsigned short, h);
}

// ---------------------------------------------------------------------------
// Kernel A: QKV projection.  out[m][n] = sum_c x[m][c] * W[n][c]
// M=16384, K=1024, N=128 per weight matrix (bn selects Wq/Wk/Wv).
// 128x128 C-tile, 4 waves (2x2 of 64x64 each), BK=32, bf16 MFMA 16x16x32.
// fp32 -> bf16 conversion happens in the staging path.
// ---------------------------------------------------------------------------
#define GS 56   // LDS row stride in ushorts: 112B, 16B-aligned, 28dw -> 2-way max

__global__ __launch_bounds__(256) void qkv_gemm(
    const float* __restrict__ x, const float* __restrict__ Wq,
    const float* __restrict__ Wk, const float* __restrict__ Wv,
    unsigned short* __restrict__ qkv)
{
    __shared__ unsigned short Al[128][GS];
    __shared__ unsigned short Bl[128][GS];
    const int bn = blockIdx.x;       // 0..2 : Q, K, V
    const int bm = blockIdx.y;       // 0..127
    const float* W = (bn == 0) ? Wq : (bn == 1) ? Wk : Wv;
    const int tid  = threadIdx.x;
    const int lane = tid & 63;
    const int w    = tid >> 6;
    const int l16  = lane & 15, lg = lane >> 4;
    const int wr = (w >> 1) * 64, wc = (w & 1) * 64;
    const int m0 = bm * 128;

    const int srow = tid >> 3;        // 0..31
    const int scol = (tid & 7) * 4;   // 0,4,...,28

    f32x4 acc[4][4] = {};

    for (int k0 = 0; k0 < C_; k0 += 32) {
        __syncthreads();
        #pragma unroll
        for (int i = 0; i < 4; i++) {
            int row = srow + 32 * i;
            float4 va = *(const float4*)(x + (size_t)(m0 + row) * C_ + k0 + scol);
            ushort4v ha = { f2b(va.x), f2b(va.y), f2b(va.z), f2b(va.w) };
            *(ushort4v*)(&Al[row][scol]) = ha;
            float4 vb = *(const float4*)(W + (size_t)row * C_ + k0 + scol);
            ushort4v hb = { f2b(vb.x), f2b(vb.y), f2b(vb.z), f2b(vb.w) };
            *(ushort4v*)(&Bl[row][scol]) = hb;
        }
        __syncthreads();
        short8 a[4], bfr[4];
        #pragma unroll
        for (int mf = 0; mf < 4; mf++)
            a[mf] = *(const short8*)(&Al[wr + 16 * mf + l16][lg * 8]);
        #pragma unroll
        for (int nf = 0; nf < 4; nf++)
            bfr[nf] = *(const short8*)(&Bl[wc + 16 * nf + l16][lg * 8]);
        #pragma unroll
        for (int mf = 0; mf < 4; mf++)
            #pragma unroll
            for (int nf = 0; nf < 4; nf++)
                acc[mf][nf] = __builtin_amdgcn_mfma_f32_16x16x32_bf16(
                    a[mf], bfr[nf], acc[mf][nf], 0, 0, 0);
    }

    // epilogue: fold softmax scale into Q
    const float scl = (bn == 0) ? 0.08838834764831845f : 1.0f;
    unsigned short* outp = qkv + (size_t)bn * T_ * B_ * D_;
    #pragma unroll
    for (int mf = 0; mf < 4; mf++) {
        #pragma unroll
        for (int nf = 0; nf < 4; nf++) {
            #pragma unroll
            for (int r = 0; r < 4; r++) {
                int row = m0 + wr + 16 * mf + lg * 4 + r;   // C/D: row=(l>>4)*4+r
                int col = wc + 16 * nf + l16;               //       col=l&15
                outp[(size_t)row * D_ + col] = f2b(acc[mf][nf][r] * scl);
            }
        }
    }
}

// ---------------------------------------------------------------------------
// Kernel B: causal flash attention forward.
// Block: 256 thr (4 waves), BQ=64 (16 q-rows/wave), K/V tiles of 64 keys.
// S = Q K^T via mfma(Qfrag, Kfrag); online softmax (rows live in 16-lane
// groups, shfl_xor reduce); P -> per-wave LDS -> A-frag; V transposed in LDS
// with key-block XOR swizzle (any 16B-aligned stride alone leaves 16-way
// write conflicts since 8-row steps are bank-neutral).
// ---------------------------------------------------------------------------
#define KSTR 136   // 272B row stride: 16B aligned, 68dw%32=4 -> 2-way
#define VSTR 72    // 144B row stride: 16B aligned, 36dw%32=4 -> 2-way
#define PSTR 72

__global__ __launch_bounds__(256) void attn_fwd(
    const unsigned short* __restrict__ Q,
    const unsigned short* __restrict__ K,
    const unsigned short* __restrict__ V,
    float* __restrict__ out)
{
    __shared__ unsigned short Kl[64][KSTR];
    __shared__ unsigned short Vt[128][VSTR];
    __shared__ unsigned short Pl[4][16][PSTR];

    const int qt = blockIdx.x;   // 0..63
    const int b  = blockIdx.y;   // 0..3
    const int q0 = qt * 64;
    const int tid  = threadIdx.x;
    const int lane = tid & 63;
    const int w    = tid >> 6;
    const int l16  = lane & 15, lg = lane >> 4;
    const size_t base = (size_t)b * T_ * D_;

    // Q fragments for this wave's 16 rows (scale pre-folded in projection)
    short8 qf[4];
    {
        const unsigned short* qp = Q + base + (size_t)(q0 + 16 * w + l16) * D_ + lg * 8;
        #pragma unroll
        for (int kf = 0; kf < 4; kf++)
            qf[kf] = *(const short8*)(qp + kf * 32);
    }

    f32x4 accO[8] = {};
    float m_r[4] = { -3e38f, -3e38f, -3e38f, -3e38f };
    float l_r[4] = { 0.f, 0.f, 0.f, 0.f };

    const int sr = tid >> 4;     // staging row 0..15
    const int sc = tid & 15;     // staging 8-elem chunk col 0..15

    for (int t = 0; t <= qt; t++) {
        const int k0 = t * 64;
        __syncthreads();   // previous tile's LDS reads done
        // stage K tile [k0, k0+64) x 128, row-major
        #pragma unroll
        for (int i = 0; i < 4; i++) {
            int kr = sr + 16 * i;
            *(short8*)(&Kl[kr][sc * 8]) =
                *(const short8*)(K + base + (size_t)(k0 + kr) * D_ + sc * 8);
        }
        // stage V transposed: Vt[d][key'] with key-block xor swizzle
        #pragma unroll
        for (int i = 0; i < 4; i++) {
            int kr = sr + 16 * i;
            short8 v = *(const short8*)(V + base + (size_t)(k0 + kr) * D_ + sc * 8);
            #pragma unroll
            for (int j = 0; j < 8; j++) {
                int dd  = sc * 8 + j;
                int col = ((((kr >> 3) ^ (dd >> 3)) & 7) << 3) | (kr & 7);
                Vt[dd][col] = (unsigned short)v[j];
            }
        }
        __syncthreads();

        // S = Q K^T  (16 q-rows x 64 keys per wave)
        f32x4 s[4] = {};
        #pragma unroll
        for (int kf = 0; kf < 4; kf++) {
            #pragma unroll
            for (int nf = 0; nf < 4; nf++) {
                short8 bk = *(const short8*)(&Kl[16 * nf + l16][kf * 32 + lg * 8]);
                s[nf] = __builtin_amdgcn_mfma_f32_16x16x32_bf16(qf[kf], bk, s[nf], 0, 0, 0);
            }
        }

        // causal mask: only the diagonal tile needs it
        if (t == qt) {
            #pragma unroll
            for (int nf = 0; nf < 4; nf++) {
                int key = k0 + 16 * nf + l16;
                #pragma unroll
                for (int r = 0; r < 4; r++) {
                    int qrow = q0 + 16 * w + lg * 4 + r;
                    if (key > qrow) s[nf][r] = -3.0e38f;
                }
            }
        }

        // online softmax; S row = lg*4 + r, distributed over 16 lanes (cols)
        float pr[4][4];
        #pragma unroll
        for (int r = 0; r < 4; r++) {
            float mx = fmaxf(fmaxf(s[0][r], s[1][r]), fmaxf(s[2][r], s[3][r]));
            mx = fmaxf(mx, __shfl_xor(mx, 1));
            mx = fmaxf(mx, __shfl_xor(mx, 2));
            mx = fmaxf(mx, __shfl_xor(mx, 4));
            mx = fmaxf(mx, __shfl_xor(mx, 8));
            float mnew  = fmaxf(m_r[r], mx);
            float alpha = __expf(m_r[r] - mnew);
            m_r[r] = mnew;
            float rs = 0.f;
            #pragma unroll
            for (int nf = 0; nf < 4; nf++) {
                float p = __expf(s[nf][r] - mnew);
                pr[nf][r] = p;
                rs += p;
            }
            rs += __shfl_xor(rs, 1);
            rs += __shfl_xor(rs, 2);
            rs += __shfl_xor(rs, 4);
            rs += __shfl_xor(rs, 8);
            l_r[r] = l_r[r] * alpha + rs;
            #pragma unroll
            for (int df = 0; df < 8; df++) accO[df][r] *= alpha;
        }

        // P -> per-wave LDS (bf16)
        #pragma unroll
        for (int nf = 0; nf < 4; nf++)
            #pragma unroll
            for (int r = 0; r < 4; r++)
                Pl[w][lg * 4 + r][16 * nf + l16] = f2b(pr[nf][r]);
        asm volatile("s_waitcnt lgkmcnt(0)" ::: "memory");

        // O += P * V
        #pragma unroll
        for (int kf = 0; kf < 2; kf++) {
            short8 ap = *(const short8*)(&Pl[w][l16][kf * 32 + lg * 8]);
            int kb = lg + 4 * kf;   // key-block index
            #pragma unroll
            for (int df = 0; df < 8; df++) {
                int dd = l16 + 16 * df;
                short8 bv = *(const short8*)(&Vt[dd][((kb ^ (dd >> 3)) & 7) << 3]);
                accO[df] = __builtin_amdgcn_mfma_f32_16x16x32_bf16(ap, bv, accO[df], 0, 0, 0);
            }
        }
    }

    // epilogue: O / l
    #pragma unroll
    for (int r = 0; r < 4; r++) {
        float inv = 1.0f / l_r[r];
        int row = q0 + 16 * w + lg * 4 + r;
        #pragma unroll
        for (int df = 0; df < 8; df++)
            out[base + (size_t)row * D_ + 16 * df + l16] = accO[df][r] * inv;
    }
}

extern "C" void kernel_launch(void* const* d_in, const int* in_sizes, int n_in,
                              void* d_out, int out_size, void* d_ws, size_t ws_size,
                              hipStream_t stream) {
    (void)in_sizes; (void)n_in; (void)out_size; (void)ws_size;
    const float* x  = (const float*)d_in[0];
    const float* Wq = (const float*)d_in[1];
    const float* Wk = (const float*)d_in[2];
    const float* Wv = (const float*)d_in[3];

    unsigned short* qkv = (unsigned short*)d_ws;   // Q | K | V, bf16, 4MB each
    qkv_gemm<<<dim3(3, 128), 256, 0, stream>>>(x, Wq, Wk, Wv, qkv);

    const unsigned short* Qw = qkv;
    const unsigned short* Kw = qkv + (size_t)T_ * B_ * D_;
    const unsigned short* Vw = qkv + 2 * (size_t)T_ * B_ * D_;
    attn_fwd<<<dim3(T_ / 64, B_), 256, 0, stream>>>(Qw, Kw, Vw, (float*)d_out);
}

// Round 2
// 148.041 us; speedup vs baseline: 1.1982x; 1.1982x over previous
//
#include <hip/hip_runtime.h>
#include <hip/hip_bf16.h>

#define B_ 4
#define T_ 4096
#define C_ 1024
#define D_ 128

typedef __attribute__((ext_vector_type(8))) short short8;
typedef __attribute__((ext_vector_type(4))) float f32x4;
typedef __attribute__((ext_vector_type(4))) unsigned short ushort4v;

static __device__ __forceinline__ unsigned short f2b(float f) {
    __hip_bfloat16 h = __float2bfloat16(f);
    return __builtin_bit_cast(unsigned short, h);
}

static __device__ __forceinline__ float exp2fast(float x) {
#if __has_builtin(__builtin_amdgcn_exp2f)
    return __builtin_amdgcn_exp2f(x);
#else
    return exp2f(x);
#endif
}

// ---------------------------------------------------------------------------
// Kernel A: fused QKV projection. 256 blocks x 512 thr (8 waves).
// M-tile 64 rows, N = 384 (Q|K|V), BK=32, double-buffered reg->LDS staging.
// x read ONCE (64MB). Q scaled by 1/sqrt(128)*log2(e) (exp2 softmax).
// V written TRANSPOSED: Vt[b][d][t]  (so attention PV B-frags are contiguous).
// ---------------------------------------------------------------------------
#define ASTR 40   // LDS row stride (elems): 20 dw -> 5*l16+lg mod 8 distinct => conflict-free b128

__global__ __launch_bounds__(512) void qkv_gemm(
    const float* __restrict__ x, const float* __restrict__ Wq,
    const float* __restrict__ Wk, const float* __restrict__ Wv,
    unsigned short* __restrict__ qkv)
{
    __shared__ unsigned short Al[2][64][ASTR];
    __shared__ unsigned short Bl[2][384][ASTR];
    const int tid  = threadIdx.x;
    const int lane = tid & 63;
    const int w    = tid >> 6;          // 0..7
    const int l16  = lane & 15, lg = lane >> 4;
    const int wr   = (w >> 2) * 32;     // 0,32
    const int wc   = (w & 3) * 96;      // 0,96,192,288
    const int m0   = blockIdx.x * 64;

    // staging: A = 1 float4/thread, B = 6 float4/thread
    const int arow = tid >> 3, ac4 = tid & 7;
    const float* aptr = x + (size_t)(m0 + arow) * C_ + ac4 * 4;
    const float* bptr[6];
    int brow[6], bc4[6];
    #pragma unroll
    for (int i = 0; i < 6; i++) {
        int id = tid + 512 * i;
        int row = id >> 3;
        brow[i] = row; bc4[i] = id & 7;
        const float* Wm = (row < 128) ? Wq : (row < 256) ? Wk : Wv;
        bptr[i] = Wm + (size_t)(row & 127) * C_ + bc4[i] * 4;
    }

    f32x4 acc[2][6] = {};
    float4 ra; float4 rb[6];

    // prologue: stage k-step 0
    ra = *(const float4*)(aptr);
    #pragma unroll
    for (int i = 0; i < 6; i++) rb[i] = *(const float4*)(bptr[i]);
    {
        ushort4v ha = { f2b(ra.x), f2b(ra.y), f2b(ra.z), f2b(ra.w) };
        *(ushort4v*)(&Al[0][arow][ac4 * 4]) = ha;
        #pragma unroll
        for (int i = 0; i < 6; i++) {
            ushort4v hb = { f2b(rb[i].x), f2b(rb[i].y), f2b(rb[i].z), f2b(rb[i].w) };
            *(ushort4v*)(&Bl[0][brow[i]][bc4[i] * 4]) = hb;
        }
    }
    __syncthreads();

    for (int ks = 0; ks < 32; ks++) {
        const int cur = ks & 1;
        if (ks < 31) {                       // issue next-tile loads early (T14)
            ra = *(const float4*)(aptr + (ks + 1) * 32);
            #pragma unroll
            for (int i = 0; i < 6; i++) rb[i] = *(const float4*)(bptr[i] + (ks + 1) * 32);
        }
        short8 a[2], b[6];
        #pragma unroll
        for (int mf = 0; mf < 2; mf++)
            a[mf] = *(const short8*)(&Al[cur][wr + 16 * mf + l16][lg * 8]);
        #pragma unroll
        for (int nf = 0; nf < 6; nf++)
            b[nf] = *(const short8*)(&Bl[cur][wc + 16 * nf + l16][lg * 8]);
        #pragma unroll
        for (int mf = 0; mf < 2; mf++)
            #pragma unroll
            for (int nf = 0; nf < 6; nf++)
                acc[mf][nf] = __builtin_amdgcn_mfma_f32_16x16x32_bf16(a[mf], b[nf], acc[mf][nf], 0, 0, 0);
        if (ks < 31) {
            const int nxt = cur ^ 1;
            ushort4v ha = { f2b(ra.x), f2b(ra.y), f2b(ra.z), f2b(ra.w) };
            *(ushort4v*)(&Al[nxt][arow][ac4 * 4]) = ha;
            #pragma unroll
            for (int i = 0; i < 6; i++) {
                ushort4v hb = { f2b(rb[i].x), f2b(rb[i].y), f2b(rb[i].z), f2b(rb[i].w) };
                *(ushort4v*)(&Bl[nxt][brow[i]][bc4[i] * 4]) = hb;
            }
        }
        __syncthreads();
    }

    // epilogue
    const float SQ = 0.08838834764831845f * 1.4426950408889634f;  // 1/sqrt(128) * log2(e)
    unsigned short* Qo = qkv;
    unsigned short* Ko = qkv + (size_t)B_ * T_ * D_;
    unsigned short* Vt = qkv + 2 * (size_t)B_ * T_ * D_;
    #pragma unroll
    for (int mf = 0; mf < 2; mf++) {
        #pragma unroll
        for (int nf = 0; nf < 6; nf++) {
            int cg  = wc + 16 * nf;     // 16-aligned -> matrix uniform per nf
            int mat = cg >> 7;
            int cc  = (cg & 127) + l16;
            #pragma unroll
            for (int r = 0; r < 4; r++) {
                int row = m0 + wr + 16 * mf + lg * 4 + r;   // C/D: row=(l>>4)*4+r, col=l&15
                float v = acc[mf][nf][r];
                if (mat == 0)      Qo[(size_t)row * D_ + cc] = f2b(v * SQ);
                else if (mat == 1) Ko[(size_t)row * D_ + cc] = f2b(v);
                else {
                    int bb = row >> 12, t = row & (T_ - 1);
                    Vt[((size_t)bb * D_ + cc) * T_ + t] = f2b(v);
                }
            }
        }
    }
}

// ---------------------------------------------------------------------------
// Kernel B: causal flash attention. 256 blocks x 256 thr (4 waves).
// Block = 64 q-rows; waves = 2 q-groups(32 rows) x 2 key-halves (in-block
// split-K, merged at the end). Per super-iter stage 128 keys of K (dbuf,
// XOR-chunk-swizzled LDS); V read direct from global Vt (contiguous frags).
// Swapped QK^T: mfma(K,Q) -> lane-local softmax rows (2 shfl_xor per reduce).
// ---------------------------------------------------------------------------
#define PSTR 72

__global__ __launch_bounds__(256) void attn_fwd(
    const unsigned short* __restrict__ Q,
    const unsigned short* __restrict__ K,
    const unsigned short* __restrict__ Vt,
    float* __restrict__ out)
{
    __shared__ unsigned short Kl[2][128 * 128];
    __shared__ unsigned short Pl[4][32][PSTR];
    __shared__ float ml_s[2][2][32][2];

    // XCD swizzle: each batch's K/Vt (2MB) lives on one XCD pair's L2
    const int bid = blockIdx.x;
    const int xcd = bid & 7;
    const int b   = xcd >> 1;
    const int qt  = ((bid >> 3) << 1) | (xcd & 1);
    const int q0  = qt * 64;

    const int tid  = threadIdx.x;
    const int lane = tid & 63;
    const int w    = tid >> 6;
    const int qg   = w >> 1, kh = w & 1;
    const int l16  = lane & 15, lg = lane >> 4;
    const int qbase = q0 + 32 * qg;
    const size_t iobase = (size_t)b * T_ * D_;
    const unsigned short* Vtb = Vt + (size_t)b * D_ * T_;

    // Q B-fragments (scale+log2e pre-folded): qf[nf][kf]
    short8 qf[2][4];
    #pragma unroll
    for (int nf = 0; nf < 2; nf++) {
        const unsigned short* qp = Q + iobase + (size_t)(qbase + 16 * nf + l16) * D_ + lg * 8;
        #pragma unroll
        for (int kf = 0; kf < 4; kf++)
            qf[nf][kf] = *(const short8*)(qp + kf * 32);
    }

    f32x4 accO[2][8] = {};
    float m_s[2] = { -1e30f, -1e30f };
    float l_s[2] = { 0.f, 0.f };

    const int nt = (qt + 2) >> 1;   // super-tiles of 128 keys

    short8 kst[8];
    auto stage_load = [&](int s) {
        #pragma unroll
        for (int i = 0; i < 8; i++) {
            int c = tid + 256 * i;
            int row = c >> 4, ck = c & 15;
            kst[i] = *(const short8*)(K + iobase + (size_t)(s * 128 + row) * D_ + ck * 8);
        }
    };
    auto stage_write = [&](int buf) {
        #pragma unroll
        for (int i = 0; i < 8; i++) {
            int c = tid + 256 * i;
            int row = c >> 4, ck = c & 15;
            *(short8*)(&Kl[buf][row * 128 + ((ck ^ (row & 7)) * 8)]) = kst[i];
        }
    };

    stage_load(0);
    stage_write(0);
    __syncthreads();

    for (int s = 0; s < nt; s++) {
        const int cur = s & 1;
        const int kb  = s * 128 + 64 * kh;
        const bool active = (kb <= qbase + 31);
        if (s + 1 < nt) stage_load(s + 1);   // prefetch issue (T14)

        if (active) {
            // V B-frags direct from global Vt (L2-resident)
            short8 vfr[2][8];
            #pragma unroll
            for (int kf2 = 0; kf2 < 2; kf2++)
                #pragma unroll
                for (int df = 0; df < 8; df++)
                    vfr[kf2][df] = *(const short8*)(Vtb + (size_t)(16 * df + l16) * T_ + kb + kf2 * 32 + lg * 8);

            // S^T = K Q^T : s2[mf][nf], key = kb+16mf+lg*4+r, q = qbase+16nf+l16
            f32x4 s2[4][2] = {};
            #pragma unroll
            for (int kf = 0; kf < 4; kf++) {
                #pragma unroll
                for (int mf = 0; mf < 4; mf++) {
                    int row = 64 * kh + 16 * mf + l16;
                    short8 ka = *(const short8*)(&Kl[cur][row * 128 + (((kf * 4 + lg) ^ (row & 7)) * 8)]);
                    #pragma unroll
                    for (int nf = 0; nf < 2; nf++)
                        s2[mf][nf] = __builtin_amdgcn_mfma_f32_16x16x32_bf16(ka, qf[nf][kf], s2[mf][nf], 0, 0, 0);
                }
            }
            // causal mask (only when tile touches the diagonal)
            if (kb + 63 > qbase) {
                #pragma unroll
                for (int mf = 0; mf < 4; mf++) {
                    int key = kb + 16 * mf + 4 * lg;
                    #pragma unroll
                    for (int nf = 0; nf < 2; nf++) {
                        int q = qbase + 16 * nf + l16;
                        #pragma unroll
                        for (int r = 0; r < 4; r++)
                            if (key + r > q) s2[mf][nf][r] = -1e30f;
                    }
                }
            }
            // online softmax (rows lane-local; reduce over lg via xor 16,32)
            float al[2];
            #pragma unroll
            for (int nf = 0; nf < 2; nf++) {
                float mx = -1e30f;
                #pragma unroll
                for (int mf = 0; mf < 4; mf++)
                    #pragma unroll
                    for (int r = 0; r < 4; r++) mx = fmaxf(mx, s2[mf][nf][r]);
                mx = fmaxf(mx, __shfl_xor(mx, 16));
                mx = fmaxf(mx, __shfl_xor(mx, 32));
                float mnew = fmaxf(m_s[nf], mx);
                al[nf] = exp2fast(m_s[nf] - mnew);
                m_s[nf] = mnew;
                float rs = 0.f;
                #pragma unroll
                for (int mf = 0; mf < 4; mf++) {
                    #pragma unroll
                    for (int r = 0; r < 4; r++) {
                        float sv = s2[mf][nf][r];
                        float p = exp2fast(sv - mnew);
                        p = (sv > -5e29f) ? p : 0.f;   // fully-masked rows stay 0
                        s2[mf][nf][r] = p;
                        rs += p;
                    }
                }
                rs += __shfl_xor(rs, 16);
                rs += __shfl_xor(rs, 32);
                l_s[nf] = l_s[nf] * al[nf] + rs;
            }
            // rescale accO (alpha broadcast: q_off = lg*4+r lives at lane lg*4+r)
            #pragma unroll
            for (int mf2 = 0; mf2 < 2; mf2++) {
                #pragma unroll
                for (int r = 0; r < 4; r++) {
                    float av = __shfl(al[mf2], ((lane >> 4) << 2) + r);
                    #pragma unroll
                    for (int df = 0; df < 8; df++) accO[mf2][df][r] *= av;
                }
            }
            // P -> per-wave LDS (row = q_off, col = key_off), packed b64
            #pragma unroll
            for (int nf = 0; nf < 2; nf++) {
                #pragma unroll
                for (int mf = 0; mf < 4; mf++) {
                    ushort4v pk = { f2b(s2[mf][nf][0]), f2b(s2[mf][nf][1]),
                                    f2b(s2[mf][nf][2]), f2b(s2[mf][nf][3]) };
                    *(ushort4v*)(&Pl[w][16 * nf + l16][16 * mf + 4 * lg]) = pk;
                }
            }
            // O += P V
            #pragma unroll
            for (int mf2 = 0; mf2 < 2; mf2++) {
                #pragma unroll
                for (int kf2 = 0; kf2 < 2; kf2++) {
                    short8 pa = *(const short8*)(&Pl[w][16 * mf2 + l16][kf2 * 32 + lg * 8]);
                    #pragma unroll
                    for (int df = 0; df < 8; df++)
                        accO[mf2][df] = __builtin_amdgcn_mfma_f32_16x16x32_bf16(pa, vfr[kf2][df], accO[mf2][df], 0, 0, 0);
                }
            }
        }
        if (s + 1 < nt) stage_write(cur ^ 1);
        __syncthreads();
    }

    // ---- cross-kh merge (in-block split-K combine) ----
    #pragma unroll
    for (int nf = 0; nf < 2; nf++) {
        ml_s[qg][kh][16 * nf + l16][0] = m_s[nf];
        ml_s[qg][kh][16 * nf + l16][1] = l_s[nf];
    }
    float* sc = (float*)&Kl[0][0];   // scratch [2][32][128] f32 (reuses K dbuf)
    if (kh == 1) {
        #pragma unroll
        for (int mf2 = 0; mf2 < 2; mf2++)
            #pragma unroll
            for (int df = 0; df < 8; df++)
                #pragma unroll
                for (int r = 0; r < 4; r++)
                    sc[(qg * 32 + 16 * mf2 + lg * 4 + r) * 128 + 16 * df + l16] = accO[mf2][df][r];
    }
    __syncthreads();
    if (kh == 0) {
        #pragma unroll
        for (int mf2 = 0; mf2 < 2; mf2++) {
            #pragma unroll
            for (int r = 0; r < 4; r++) {
                int qoff = 16 * mf2 + lg * 4 + r;
                float ma = ml_s[qg][0][qoff][0], la = ml_s[qg][0][qoff][1];
                float mb = ml_s[qg][1][qoff][0], lb = ml_s[qg][1][qoff][1];
                float m12 = fmaxf(ma, mb);
                float fa = exp2fast(ma - m12);
                float fb = exp2fast(mb - m12);
                float inv = 1.0f / (fa * la + fb * lb);
                int qrow = qbase + qoff;
                #pragma unroll
                for (int df = 0; df < 8; df++) {
                    float vb2 = sc[(qg * 32 + qoff) * 128 + 16 * df + l16];
                    out[iobase + (size_t)qrow * D_ + 16 * df + l16] =
                        (fa * accO[mf2][df][r] + fb * vb2) * inv;
                }
            }
        }
    }
}

extern "C" void kernel_launch(void* const* d_in, const int* in_sizes, int n_in,
                              void* d_out, int out_size, void* d_ws, size_t ws_size,
                              hipStream_t stream) {
    (void)in_sizes; (void)n_in; (void)out_size; (void)ws_size;
    const float* x  = (const float*)d_in[0];
    const float* Wq = (const float*)d_in[1];
    const float* Wk = (const float*)d_in[2];
    const float* Wv = (const float*)d_in[3];

    unsigned short* qkv = (unsigned short*)d_ws;   // Q | K | Vt, bf16, 4MB each
    qkv_gemm<<<dim3(256), 512, 0, stream>>>(x, Wq, Wk, Wv, qkv);

    const unsigned short* Qw = qkv;
    const unsigned short* Kw = qkv + (size_t)B_ * T_ * D_;
    const unsigned short* Vw = qkv + 2 * (size_t)B_ * T_ * D_;
    attn_fwd<<<dim3(256), 256, 0, stream>>>(Qw, Kw, Vw, (float*)d_out);
}

// Round 3
// 104.440 us; speedup vs baseline: 1.6984x; 1.4175x over previous
//
#include <hip/hip_runtime.h>
#include <hip/hip_bf16.h>

#define B_ 4
#define T_ 4096
#define C_ 1024
#define D_ 128

typedef __attribute__((ext_vector_type(8))) short short8;
typedef __attribute__((ext_vector_type(4))) float f32x4;
typedef __attribute__((ext_vector_type(4))) unsigned short ushort4v;

static __device__ __forceinline__ unsigned short f2b(float f) {
    __hip_bfloat16 h = __float2bfloat16(f);
    return __builtin_bit_cast(unsigned short, h);
}

static __device__ __forceinline__ float exp2fast(float x) {
#if __has_builtin(__builtin_amdgcn_exp2f)
    return __builtin_amdgcn_exp2f(x);
#else
    return exp2f(x);
#endif
}

// ---------------------------------------------------------------------------
// Kernel 0: W -> bf16 (Q|K|V rows concatenated: [384][1024])
// ---------------------------------------------------------------------------
__global__ __launch_bounds__(256) void wcvt(
    const float* __restrict__ Wq, const float* __restrict__ Wk,
    const float* __restrict__ Wv, unsigned short* __restrict__ Wb)
{
    int idx = (blockIdx.x * 256 + threadIdx.x) * 8;
    const float* src = (idx < 131072) ? (Wq + idx)
                     : (idx < 262144) ? (Wk + idx - 131072)
                                      : (Wv + idx - 262144);
    float4 a = *(const float4*)src;
    float4 c = *(const float4*)(src + 4);
    short8 o = { (short)f2b(a.x), (short)f2b(a.y), (short)f2b(a.z), (short)f2b(a.w),
                 (short)f2b(c.x), (short)f2b(c.y), (short)f2b(c.z), (short)f2b(c.w) };
    *(short8*)(Wb + idx) = o;
}

// ---------------------------------------------------------------------------
// Kernel A: fused QKV projection. 256 blocks x 512 thr (8 waves = 2m x 4n).
// Tile 64m x 384n, BK=64, dbuf, XOR-swizzled LDS (conflict-free b128).
// x read once (fp32->bf16 in staging); W from pre-converted Wb.
// Q scaled by 1/sqrt(128)*log2(e); V written as panels Vp[b][t/32][d][t%32].
// ---------------------------------------------------------------------------
__global__ __launch_bounds__(512, 2) void qkv_gemm(
    const float* __restrict__ x, const unsigned short* __restrict__ Wb,
    unsigned short* __restrict__ qkv)
{
    __shared__ unsigned short Al[2][64][64];
    __shared__ unsigned short Bl[2][384][64];
    const int tid = threadIdx.x, lane = tid & 63, w = tid >> 6;
    const int l16 = lane & 15, lg = lane >> 4;
    const int wr = (w >> 2) << 5;       // 0,32
    const int wc = (w & 3) * 96;        // 0,96,192,288
    const int m0 = blockIdx.x << 6;

    const int arow = tid >> 3, ac = tid & 7;
    const float* aptr = x + (size_t)(m0 + arow) * C_ + (ac << 3);
    int brow[6], bc[6];
    #pragma unroll
    for (int i = 0; i < 6; i++) { int cl = tid + (i << 9); brow[i] = cl >> 3; bc[i] = cl & 7; }

    f32x4 acc[2][6] = {};
    float4 ra0, ra1; short8 rbv[6];

    // prologue: stage k-step 0 into buf 0
    ra0 = *(const float4*)(aptr);
    ra1 = *(const float4*)(aptr + 4);
    #pragma unroll
    for (int i = 0; i < 6; i++) rbv[i] = *(const short8*)(Wb + (size_t)brow[i] * C_ + (bc[i] << 3));
    {
        short8 ha = { (short)f2b(ra0.x), (short)f2b(ra0.y), (short)f2b(ra0.z), (short)f2b(ra0.w),
                      (short)f2b(ra1.x), (short)f2b(ra1.y), (short)f2b(ra1.z), (short)f2b(ra1.w) };
        *(short8*)(&Al[0][arow][(ac ^ (arow & 7)) << 3]) = ha;
        #pragma unroll
        for (int i = 0; i < 6; i++)
            *(short8*)(&Bl[0][brow[i]][(bc[i] ^ (brow[i] & 7)) << 3]) = rbv[i];
    }
    __syncthreads();

    for (int ks = 0; ks < 16; ks++) {
        const int cur = ks & 1;
        if (ks < 15) {
            const int k0 = (ks + 1) << 6;
            ra0 = *(const float4*)(aptr + k0);
            ra1 = *(const float4*)(aptr + k0 + 4);
            #pragma unroll
            for (int i = 0; i < 6; i++)
                rbv[i] = *(const short8*)(Wb + (size_t)brow[i] * C_ + k0 + (bc[i] << 3));
        }
        short8 af[2][2], bf[6][2];
        #pragma unroll
        for (int mf = 0; mf < 2; mf++) {
            int row = wr + (mf << 4) + l16;
            #pragma unroll
            for (int kf = 0; kf < 2; kf++)
                af[mf][kf] = *(const short8*)(&Al[cur][row][((((kf << 2) + lg) ^ (row & 7)) << 3)]);
        }
        #pragma unroll
        for (int nf = 0; nf < 6; nf++) {
            int row = wc + (nf << 4) + l16;
            #pragma unroll
            for (int kf = 0; kf < 2; kf++)
                bf[nf][kf] = *(const short8*)(&Bl[cur][row][((((kf << 2) + lg) ^ (row & 7)) << 3)]);
        }
        #pragma unroll
        for (int kf = 0; kf < 2; kf++)
            #pragma unroll
            for (int mf = 0; mf < 2; mf++)
                #pragma unroll
                for (int nf = 0; nf < 6; nf++)
                    acc[mf][nf] = __builtin_amdgcn_mfma_f32_16x16x32_bf16(af[mf][kf], bf[nf][kf], acc[mf][nf], 0, 0, 0);
        if (ks < 15) {
            const int nxt = cur ^ 1;
            short8 ha = { (short)f2b(ra0.x), (short)f2b(ra0.y), (short)f2b(ra0.z), (short)f2b(ra0.w),
                          (short)f2b(ra1.x), (short)f2b(ra1.y), (short)f2b(ra1.z), (short)f2b(ra1.w) };
            *(short8*)(&Al[nxt][arow][(ac ^ (arow & 7)) << 3]) = ha;
            #pragma unroll
            for (int i = 0; i < 6; i++)
                *(short8*)(&Bl[nxt][brow[i]][(bc[i] ^ (brow[i] & 7)) << 3]) = rbv[i];
        }
        __syncthreads();
    }

    // epilogue
    const float SQ = 0.08838834764831845f * 1.4426950408889634f;  // 1/sqrt(128)*log2e
    unsigned short* Qo = qkv;
    unsigned short* Ko = qkv + (size_t)B_ * T_ * D_;
    unsigned short* Vp = qkv + 2 * (size_t)B_ * T_ * D_;
    #pragma unroll
    for (int mf = 0; mf < 2; mf++) {
        #pragma unroll
        for (int nf = 0; nf < 6; nf++) {
            int cg  = wc + (nf << 4);
            int mat = cg >> 7;
            int cc  = (cg & 127) + l16;
            #pragma unroll
            for (int r = 0; r < 4; r++) {
                int row = m0 + wr + (mf << 4) + (lg << 2) + r;
                float v = acc[mf][nf][r];
                if (mat == 0)      Qo[(size_t)row * D_ + cc] = f2b(v * SQ);
                else if (mat == 1) Ko[(size_t)row * D_ + cc] = f2b(v);
                else {
                    int t = row & (T_ - 1), bb = row >> 12;
                    Vp[((((size_t)bb * 128 + (t >> 5)) << 7) | cc) * 32 + (t & 31)] = f2b(v);
                }
            }
        }
    }
}

// ---------------------------------------------------------------------------
// Kernel B: causal flash attention. 256 blocks x 256 thr (4 waves).
// Block p (of batch b via XCD swizzle) handles q-tiles {p, 127-p} (32 rows
// each) -> EVERY block does exactly 33 super-iters (perfect balance).
// Per 128-key super-iter: wave w owns keys [128s+32w, +32) (split-K, merged
// once per tile). K staged in dbuf XOR-swizzled LDS; V read coalesced from
// global panels Vp[kp][d][32] (L2-resident). Swapped QK^T (mfma(K,Q)) ->
// lane-local softmax rows, 2 shfl per reduce.
// ---------------------------------------------------------------------------
__global__ __launch_bounds__(256, 1) void attn_fwd(
    const unsigned short* __restrict__ Q,
    const unsigned short* __restrict__ K,
    const unsigned short* __restrict__ Vp,
    float* __restrict__ out)
{
    __shared__ __align__(16) unsigned char smem[65536 + 10240 + 1024];
    auto* Kl  = (unsigned short (*)[16384])smem;             // [2][128*128]
    auto* Pl  = (unsigned short (*)[32][40])(smem + 65536);  // [4][32][40]
    float* mlS = (float*)(smem + 65536 + 10240);             // [4][32][2]
    float* sc  = (float*)smem;                               // merge scratch [4][32][132]

    const int beta = blockIdx.x;
    const int xcd  = beta & 7;
    const int b    = xcd >> 1;
    const int p    = ((beta >> 3) << 1) | (xcd & 1);   // 0..63

    const int tid = threadIdx.x, lane = tid & 63, w = tid >> 6;
    const int l16 = lane & 15, lg = lane >> 4;
    const size_t base = (size_t)b * T_ * D_;
    const unsigned short* Kb  = K + base;
    const unsigned short* Vpb = Vp + ((size_t)b << 19);

    short8 kst[8];
    auto kload = [&](int k0) {
        #pragma unroll
        for (int i = 0; i < 8; i++) {
            int c = (i << 8) + tid;
            int row = c >> 4, ck = c & 15;
            kst[i] = *(const short8*)(Kb + (size_t)(k0 + row) * D_ + (ck << 3));
        }
    };
    auto kwrite = [&](int buf) {
        #pragma unroll
        for (int i = 0; i < 8; i++) {
            int c = (i << 8) + tid;
            int row = c >> 4, ck = c & 15;
            *(short8*)(&Kl[buf][(row << 7) + ((ck ^ (row & 7)) << 3)]) = kst[i];
        }
    };

    #pragma unroll 1
    for (int half = 0; half < 2; half++) {
        const int it = half ? (127 - p) : p;
        const int qb = it << 5;
        const int ns = (it >> 2) + 1;

        // Q B-fragments (scale+log2e folded in projection)
        short8 qf[2][4];
        #pragma unroll
        for (int nf = 0; nf < 2; nf++) {
            const unsigned short* qp = Q + base + (size_t)(qb + (nf << 4) + l16) * D_ + (lg << 3);
            #pragma unroll
            for (int kf = 0; kf < 4; kf++)
                qf[nf][kf] = *(const short8*)(qp + (kf << 5));
        }
        f32x4 accO[2][8] = {};
        float m_s[2] = { -1e30f, -1e30f };
        float l_s[2] = { 0.f, 0.f };

        kload(0);
        kwrite(0);
        __syncthreads();

        for (int s = 0; s < ns; s++) {
            const int cur = s & 1;
            const int kb  = (s << 7) + (w << 5);
            const bool act = (kb <= qb + 31);
            if (s + 1 < ns) kload((s + 1) << 7);

            if (act) {
                // V B-frags, perfectly coalesced from L2-resident panels
                const unsigned short* vp = Vpb + ((size_t)(kb >> 5) << 12) + (l16 << 5) + (lg << 3);
                short8 bv[8];
                #pragma unroll
                for (int df = 0; df < 8; df++) bv[df] = *(const short8*)(vp + (df << 9));

                // S^T = K Q^T : key = kb + 16mf + 4lg + r, q = qb + 16nf + l16
                f32x4 s2[2][2] = {};
                #pragma unroll
                for (int kf = 0; kf < 4; kf++) {
                    #pragma unroll
                    for (int mf = 0; mf < 2; mf++) {
                        int row = (w << 5) + (mf << 4) + l16;
                        short8 ka = *(const short8*)(&Kl[cur][(row << 7) + (((((kf << 2) + lg)) ^ (row & 7)) << 3)]);
                        #pragma unroll
                        for (int nf = 0; nf < 2; nf++)
                            s2[mf][nf] = __builtin_amdgcn_mfma_f32_16x16x32_bf16(ka, qf[nf][kf], s2[mf][nf], 0, 0, 0);
                    }
                }
                // causal mask
                if (kb + 31 > qb) {
                    #pragma unroll
                    for (int mf = 0; mf < 2; mf++) {
                        int key = kb + (mf << 4) + (lg << 2);
                        #pragma unroll
                        for (int nf = 0; nf < 2; nf++) {
                            int q = qb + (nf << 4) + l16;
                            #pragma unroll
                            for (int r = 0; r < 4; r++)
                                if (key + r > q) s2[mf][nf][r] = -1e30f;
                        }
                    }
                }
                // online softmax (rows lane-local; reduce over lg: xor 16,32)
                float al[2];
                #pragma unroll
                for (int nf = 0; nf < 2; nf++) {
                    float mx = fmaxf(fmaxf(fmaxf(s2[0][nf][0], s2[0][nf][1]), fmaxf(s2[0][nf][2], s2[0][nf][3])),
                                     fmaxf(fmaxf(s2[1][nf][0], s2[1][nf][1]), fmaxf(s2[1][nf][2], s2[1][nf][3])));
                    mx = fmaxf(mx, __shfl_xor(mx, 16));
                    mx = fmaxf(mx, __shfl_xor(mx, 32));
                    float mnew = fmaxf(m_s[nf], mx);
                    al[nf] = exp2fast(m_s[nf] - mnew);
                    m_s[nf] = mnew;
                    float rs = 0.f;
                    #pragma unroll
                    for (int mf = 0; mf < 2; mf++)
                        #pragma unroll
                        for (int r = 0; r < 4; r++) {
                            float sv = s2[mf][nf][r];
                            float pv2 = exp2fast(sv - mnew);
                            pv2 = (sv > -5e29f) ? pv2 : 0.f;
                            s2[mf][nf][r] = pv2;
                            rs += pv2;
                        }
                    rs += __shfl_xor(rs, 16);
                    rs += __shfl_xor(rs, 32);
                    l_s[nf] = l_s[nf] * al[nf] + rs;
                }
                // rescale accO
                #pragma unroll
                for (int qi = 0; qi < 2; qi++) {
                    #pragma unroll
                    for (int r = 0; r < 4; r++) {
                        float av = __shfl(al[qi], (lg << 2) + r);
                        #pragma unroll
                        for (int df = 0; df < 8; df++) accO[qi][df][r] *= av;
                    }
                }
                // P -> per-wave LDS
                #pragma unroll
                for (int nf = 0; nf < 2; nf++)
                    #pragma unroll
                    for (int mf = 0; mf < 2; mf++) {
                        ushort4v pk = { f2b(s2[mf][nf][0]), f2b(s2[mf][nf][1]),
                                        f2b(s2[mf][nf][2]), f2b(s2[mf][nf][3]) };
                        *(ushort4v*)(&Pl[w][(nf << 4) + l16][(mf << 4) + (lg << 2)]) = pk;
                    }
                // O += P V
                #pragma unroll
                for (int qi = 0; qi < 2; qi++) {
                    short8 pa = *(const short8*)(&Pl[w][(qi << 4) + l16][lg << 3]);
                    #pragma unroll
                    for (int df = 0; df < 8; df++)
                        accO[qi][df] = __builtin_amdgcn_mfma_f32_16x16x32_bf16(pa, bv[df], accO[qi][df], 0, 0, 0);
                }
            }
            if (s + 1 < ns) kwrite(cur ^ 1);
            __syncthreads();
        }

        // ---- 4-way split-K merge (scratch aliases Kl; all reads of Kl done) ----
        if (lg == 0) {
            #pragma unroll
            for (int nf = 0; nf < 2; nf++) {
                mlS[((w << 5) + (nf << 4) + l16) * 2 + 0] = m_s[nf];
                mlS[((w << 5) + (nf << 4) + l16) * 2 + 1] = l_s[nf];
            }
        }
        #pragma unroll
        for (int qi = 0; qi < 2; qi++)
            #pragma unroll
            for (int df = 0; df < 8; df++)
                #pragma unroll
                for (int r = 0; r < 4; r++)
                    sc[((w << 5) + (qi << 4) + (lg << 2) + r) * 132 + (df << 4) + l16] = accO[qi][df][r];
        __syncthreads();
        {
            int row = tid >> 3, cb = (tid & 7) << 4;
            float m0v = mlS[(row) * 2],        l0v = mlS[(row) * 2 + 1];
            float m1v = mlS[(32 + row) * 2],   l1v = mlS[(32 + row) * 2 + 1];
            float m2v = mlS[(64 + row) * 2],   l2v = mlS[(64 + row) * 2 + 1];
            float m3v = mlS[(96 + row) * 2],   l3v = mlS[(96 + row) * 2 + 1];
            float mst = fmaxf(fmaxf(m0v, m1v), fmaxf(m2v, m3v));
            float f0 = exp2fast(m0v - mst), f1 = exp2fast(m1v - mst);
            float f2 = exp2fast(m2v - mst), f3 = exp2fast(m3v - mst);
            float inv = 1.0f / (f0 * l0v + f1 * l1v + f2 * l2v + f3 * l3v);
            #pragma unroll
            for (int j = 0; j < 4; j++) {
                int col = cb + (j << 2);
                f32x4 o = f0 * *(const f32x4*)&sc[(row) * 132 + col]
                        + f1 * *(const f32x4*)&sc[(32 + row) * 132 + col]
                        + f2 * *(const f32x4*)&sc[(64 + row) * 132 + col]
                        + f3 * *(const f32x4*)&sc[(96 + row) * 132 + col];
                *(f32x4*)(out + base + (size_t)(qb + row) * D_ + col) = o * inv;
            }
        }
        __syncthreads();
    }
}

extern "C" void kernel_launch(void* const* d_in, const int* in_sizes, int n_in,
                              void* d_out, int out_size, void* d_ws, size_t ws_size,
                              hipStream_t stream) {
    (void)in_sizes; (void)n_in; (void)out_size; (void)ws_size;
    const float* x  = (const float*)d_in[0];
    const float* Wq = (const float*)d_in[1];
    const float* Wk = (const float*)d_in[2];
    const float* Wv = (const float*)d_in[3];

    unsigned short* qkv = (unsigned short*)d_ws;     // Q | K | Vp, bf16, 4MB each
    unsigned short* Wb  = (unsigned short*)d_out;    // temp bf16 W (overwritten by attn)

    wcvt<<<dim3(192), 256, 0, stream>>>(Wq, Wk, Wv, Wb);
    qkv_gemm<<<dim3(256), 512, 0, stream>>>(x, Wb, qkv);

    const unsigned short* Qw = qkv;
    const unsigned short* Kw = qkv + (size_t)B_ * T_ * D_;
    const unsigned short* Vw = qkv + 2 * (size_t)B_ * T_ * D_;
    attn_fwd<<<dim3(256), 256, 0, stream>>>(Qw, Kw, Vw, (float*)d_out);
}

// Round 4
// 96.938 us; speedup vs baseline: 1.8299x; 1.0774x over previous
//
#include <hip/hip_runtime.h>
#include <hip/hip_bf16.h>

#define B_ 4
#define T_ 4096
#define C_ 1024
#define D_ 128

typedef __attribute__((ext_vector_type(8))) short short8;
typedef __attribute__((ext_vector_type(4))) float f32x4;
typedef __attribute__((ext_vector_type(4))) unsigned short ushort4v;

static __device__ __forceinline__ unsigned short f2b(float f) {
    __hip_bfloat16 h = __float2bfloat16(f);
    return __builtin_bit_cast(unsigned short, h);
}

static __device__ __forceinline__ float exp2fast(float x) {
#if __has_builtin(__builtin_amdgcn_exp2f)
    return __builtin_amdgcn_exp2f(x);
#else
    return exp2f(x);
#endif
}

// ---------------------------------------------------------------------------
// Kernel 0: W -> bf16 (Q|K|V rows concatenated: [384][1024])
// ---------------------------------------------------------------------------
__global__ __launch_bounds__(256) void wcvt(
    const float* __restrict__ Wq, const float* __restrict__ Wk,
    const float* __restrict__ Wv, unsigned short* __restrict__ Wb)
{
    int idx = (blockIdx.x * 256 + threadIdx.x) * 8;
    const float* src = (idx < 131072) ? (Wq + idx)
                     : (idx < 262144) ? (Wk + idx - 131072)
                                      : (Wv + idx - 262144);
    float4 a = *(const float4*)src;
    float4 c = *(const float4*)(src + 4);
    short8 o = { (short)f2b(a.x), (short)f2b(a.y), (short)f2b(a.z), (short)f2b(a.w),
                 (short)f2b(c.x), (short)f2b(c.y), (short)f2b(c.z), (short)f2b(c.w) };
    *(short8*)(Wb + idx) = o;
}

// ---------------------------------------------------------------------------
// Kernel A: fused QKV projection. 256 blocks x 512 thr (8 waves = 2m x 4n).
// Tile 64m x 384n, BK=64, dbuf, XOR-swizzled LDS (conflict-free b128).
// x read once (fp32->bf16 in staging); W from pre-converted Wb.
// Q scaled by 1/sqrt(128)*log2(e); V written as panels Vp[b][t/32][d][t%32].
// ---------------------------------------------------------------------------
__global__ __launch_bounds__(512, 2) void qkv_gemm(
    const float* __restrict__ x, const unsigned short* __restrict__ Wb,
    unsigned short* __restrict__ qkv)
{
    __shared__ unsigned short Al[2][64][64];
    __shared__ unsigned short Bl[2][384][64];
    const int tid = threadIdx.x, lane = tid & 63, w = tid >> 6;
    const int l16 = lane & 15, lg = lane >> 4;
    const int wr = (w >> 2) << 5;       // 0,32
    const int wc = (w & 3) * 96;        // 0,96,192,288
    const int m0 = blockIdx.x << 6;

    const int arow = tid >> 3, ac = tid & 7;
    const float* aptr = x + (size_t)(m0 + arow) * C_ + (ac << 3);
    int brow[6], bc[6];
    #pragma unroll
    for (int i = 0; i < 6; i++) { int cl = tid + (i << 9); brow[i] = cl >> 3; bc[i] = cl & 7; }

    f32x4 acc[2][6] = {};
    float4 ra0, ra1; short8 rbv[6];

    // prologue: stage k-step 0 into buf 0
    ra0 = *(const float4*)(aptr);
    ra1 = *(const float4*)(aptr + 4);
    #pragma unroll
    for (int i = 0; i < 6; i++) rbv[i] = *(const short8*)(Wb + (size_t)brow[i] * C_ + (bc[i] << 3));
    {
        short8 ha = { (short)f2b(ra0.x), (short)f2b(ra0.y), (short)f2b(ra0.z), (short)f2b(ra0.w),
                      (short)f2b(ra1.x), (short)f2b(ra1.y), (short)f2b(ra1.z), (short)f2b(ra1.w) };
        *(short8*)(&Al[0][arow][(ac ^ (arow & 7)) << 3]) = ha;
        #pragma unroll
        for (int i = 0; i < 6; i++)
            *(short8*)(&Bl[0][brow[i]][(bc[i] ^ (brow[i] & 7)) << 3]) = rbv[i];
    }
    __syncthreads();

    for (int ks = 0; ks < 16; ks++) {
        const int cur = ks & 1;
        if (ks < 15) {
            const int k0 = (ks + 1) << 6;
            ra0 = *(const float4*)(aptr + k0);
            ra1 = *(const float4*)(aptr + k0 + 4);
            #pragma unroll
            for (int i = 0; i < 6; i++)
                rbv[i] = *(const short8*)(Wb + (size_t)brow[i] * C_ + k0 + (bc[i] << 3));
        }
        short8 af[2][2], bf[6][2];
        #pragma unroll
        for (int mf = 0; mf < 2; mf++) {
            int row = wr + (mf << 4) + l16;
            #pragma unroll
            for (int kf = 0; kf < 2; kf++)
                af[mf][kf] = *(const short8*)(&Al[cur][row][((((kf << 2) + lg) ^ (row & 7)) << 3)]);
        }
        #pragma unroll
        for (int nf = 0; nf < 6; nf++) {
            int row = wc + (nf << 4) + l16;
            #pragma unroll
            for (int kf = 0; kf < 2; kf++)
                bf[nf][kf] = *(const short8*)(&Bl[cur][row][((((kf << 2) + lg) ^ (row & 7)) << 3)]);
        }
        #pragma unroll
        for (int kf = 0; kf < 2; kf++)
            #pragma unroll
            for (int mf = 0; mf < 2; mf++)
                #pragma unroll
                for (int nf = 0; nf < 6; nf++)
                    acc[mf][nf] = __builtin_amdgcn_mfma_f32_16x16x32_bf16(af[mf][kf], bf[nf][kf], acc[mf][nf], 0, 0, 0);
        if (ks < 15) {
            const int nxt = cur ^ 1;
            short8 ha = { (short)f2b(ra0.x), (short)f2b(ra0.y), (short)f2b(ra0.z), (short)f2b(ra0.w),
                          (short)f2b(ra1.x), (short)f2b(ra1.y), (short)f2b(ra1.z), (short)f2b(ra1.w) };
            *(short8*)(&Al[nxt][arow][(ac ^ (arow & 7)) << 3]) = ha;
            #pragma unroll
            for (int i = 0; i < 6; i++)
                *(short8*)(&Bl[nxt][brow[i]][(bc[i] ^ (brow[i] & 7)) << 3]) = rbv[i];
        }
        __syncthreads();
    }

    // epilogue
    const float SQ = 0.08838834764831845f * 1.4426950408889634f;  // 1/sqrt(128)*log2e
    unsigned short* Qo = qkv;
    unsigned short* Ko = qkv + (size_t)B_ * T_ * D_;
    unsigned short* Vp = qkv + 2 * (size_t)B_ * T_ * D_;
    #pragma unroll
    for (int mf = 0; mf < 2; mf++) {
        #pragma unroll
        for (int nf = 0; nf < 6; nf++) {
            int cg  = wc + (nf << 4);
            int mat = cg >> 7;
            int cc  = (cg & 127) + l16;
            #pragma unroll
            for (int r = 0; r < 4; r++) {
                int row = m0 + wr + (mf << 4) + (lg << 2) + r;
                float v = acc[mf][nf][r];
                if (mat == 0)      Qo[(size_t)row * D_ + cc] = f2b(v * SQ);
                else if (mat == 1) Ko[(size_t)row * D_ + cc] = f2b(v);
                else {
                    int t = row & (T_ - 1), bb = row >> 12;
                    Vp[((((size_t)bb * 128 + (t >> 5)) << 7) | cc) * 32 + (t & 31)] = f2b(v);
                }
            }
        }
    }
}

// ---------------------------------------------------------------------------
// Kernel B: causal flash attention. 256 blocks x 512 thr (8 waves/CU = 2/SIMD).
// Block p (batch via XCD swizzle) handles q-tiles {p, 127-p} (32 rows each)
// sequentially -> every block does exactly 33 super-iters of 128 keys.
// Waves: qs = w>>2 picks 16-row q-subtile, kh = w&3 picks 32-key slice
// (split-K, merged once per tile). K staged in dbuf XOR-swizzled LDS
// (shared by all 8 waves); V read coalesced (1KB/instr) from global panels
// Vp[kp][d][32] (L2-resident). Swapped QK^T (mfma(K,Q)) -> lane-local
// softmax rows, 2 shfl per reduce. 2 waves/SIMD overlaps softmax with MFMA.
// ---------------------------------------------------------------------------
__global__ __launch_bounds__(512, 2) void attn_fwd(
    const unsigned short* __restrict__ Q,
    const unsigned short* __restrict__ K,
    const unsigned short* __restrict__ Vp,
    float* __restrict__ out)
{
    __shared__ __align__(16) unsigned char smem[65536 + 10240 + 1024];
    auto* Kl  = (unsigned short (*)[16384])smem;             // [2][128*128]
    auto* Pl  = (unsigned short (*)[16][40])(smem + 65536);  // [8][16][40]
    float* mlS = (float*)(smem + 65536 + 10240);             // [2][4][16][2]
    float* scf = (float*)smem;                               // merge scratch [6][16][130] f32 (aliases Kl)

    const int beta = blockIdx.x;
    const int xcd  = beta & 7;
    const int b    = xcd >> 1;
    const int p    = ((beta >> 3) << 1) | (xcd & 1);   // 0..63

    const int tid = threadIdx.x, lane = tid & 63, w = tid >> 6;
    const int qs = w >> 2, kh = w & 3;
    const int l16 = lane & 15, lg = lane >> 4;
    const size_t base = (size_t)b * T_ * D_;
    const unsigned short* Kb  = K + base;
    const unsigned short* Vpb = Vp + ((size_t)b << 19);

    short8 kst[4];
    auto kload = [&](int k0) {
        #pragma unroll
        for (int i = 0; i < 4; i++) {
            int c = (i << 9) + tid;
            int row = c >> 4, ck = c & 15;
            kst[i] = *(const short8*)(Kb + (size_t)(k0 + row) * D_ + (ck << 3));
        }
    };
    auto kwrite = [&](int buf) {
        #pragma unroll
        for (int i = 0; i < 4; i++) {
            int c = (i << 9) + tid;
            int row = c >> 4, ck = c & 15;
            *(short8*)(&Kl[buf][(row << 7) + ((ck ^ (row & 7)) << 3)]) = kst[i];
        }
    };

    #pragma unroll 1
    for (int half = 0; half < 2; half++) {
        const int it = half ? (127 - p) : p;
        const int qb = it << 5;
        const int qrow0 = qb + (qs << 4);        // wave's first q row
        const int ns = (it >> 2) + 1;

        // Q B-fragments (scale+log2e folded in projection)
        short8 qf[4];
        {
            const unsigned short* qp = Q + base + (size_t)(qrow0 + l16) * D_ + (lg << 3);
            #pragma unroll
            for (int kf = 0; kf < 4; kf++)
                qf[kf] = *(const short8*)(qp + (kf << 5));
        }
        f32x4 accO[8] = {};
        float m_s = -1e30f;
        float l_s = 0.f;

        kload(0);
        kwrite(0);
        __syncthreads();

        for (int s = 0; s < ns; s++) {
            const int cur = s & 1;
            const int kb  = (s << 7) + (kh << 5);
            const bool act = (kb <= qrow0 + 15);
            if (s + 1 < ns) kload((s + 1) << 7);   // prefetch issue (hides under compute)

            if (act) {
                // V B-frags: 1KB-coalesced from L2-resident panels
                const unsigned short* vp = Vpb + ((size_t)(kb >> 5) << 12) + (l16 << 5) + (lg << 3);
                short8 bv[8];
                #pragma unroll
                for (int df = 0; df < 8; df++) bv[df] = *(const short8*)(vp + (df << 9));

                // S^T = K Q^T : key = kb + 16mf + 4lg + r, q = qrow0 + l16
                f32x4 s2[2] = {};
                #pragma unroll
                for (int kf = 0; kf < 4; kf++) {
                    #pragma unroll
                    for (int mf = 0; mf < 2; mf++) {
                        int row = (kh << 5) + (mf << 4) + l16;
                        short8 ka = *(const short8*)(&Kl[cur][(row << 7) + (((((kf << 2) + lg)) ^ (row & 7)) << 3)]);
                        s2[mf] = __builtin_amdgcn_mfma_f32_16x16x32_bf16(ka, qf[kf], s2[mf], 0, 0, 0);
                    }
                }
                // causal mask (only when slice touches the diagonal)
                if (kb + 31 > qrow0) {
                    #pragma unroll
                    for (int mf = 0; mf < 2; mf++) {
                        int key = kb + (mf << 4) + (lg << 2);
                        int q = qrow0 + l16;
                        #pragma unroll
                        for (int r = 0; r < 4; r++)
                            if (key + r > q) s2[mf][r] = -1e30f;
                    }
                }
                // online softmax (row lane-local; reduce over lg: xor 16,32)
                float mx = fmaxf(fmaxf(fmaxf(s2[0][0], s2[0][1]), fmaxf(s2[0][2], s2[0][3])),
                                 fmaxf(fmaxf(s2[1][0], s2[1][1]), fmaxf(s2[1][2], s2[1][3])));
                mx = fmaxf(mx, __shfl_xor(mx, 16));
                mx = fmaxf(mx, __shfl_xor(mx, 32));
                float mnew = fmaxf(m_s, mx);
                float al = exp2fast(m_s - mnew);
                m_s = mnew;
                float rs = 0.f;
                #pragma unroll
                for (int mf = 0; mf < 2; mf++)
                    #pragma unroll
                    for (int r = 0; r < 4; r++) {
                        float sv = s2[mf][r];
                        float pv2 = exp2fast(sv - mnew);
                        pv2 = (sv > -5e29f) ? pv2 : 0.f;   // fully-masked rows stay 0
                        s2[mf][r] = pv2;
                        rs += pv2;
                    }
                rs += __shfl_xor(rs, 16);
                rs += __shfl_xor(rs, 32);
                l_s = l_s * al + rs;
                // rescale accO (alpha for q-off 4lg+r lives at lane 4lg+r)
                #pragma unroll
                for (int r = 0; r < 4; r++) {
                    float av = __shfl(al, (lg << 2) + r);
                    #pragma unroll
                    for (int df = 0; df < 8; df++) accO[df][r] *= av;
                }
                // P -> per-wave LDS
                #pragma unroll
                for (int mf = 0; mf < 2; mf++) {
                    ushort4v pk = { f2b(s2[mf][0]), f2b(s2[mf][1]),
                                    f2b(s2[mf][2]), f2b(s2[mf][3]) };
                    *(ushort4v*)(&Pl[w][l16][(mf << 4) + (lg << 2)]) = pk;
                }
                // O += P V
                short8 pa = *(const short8*)(&Pl[w][l16][lg << 3]);
                #pragma unroll
                for (int df = 0; df < 8; df++)
                    accO[df] = __builtin_amdgcn_mfma_f32_16x16x32_bf16(pa, bv[df], accO[df], 0, 0, 0);
            }
            if (s + 1 < ns) kwrite(cur ^ 1);
            __syncthreads();
        }

        // ---- 4-way split-K merge (scf aliases Kl; all K reads done) ----
        if (lg == 0) {
            mlS[((qs << 2) + kh) * 32 + l16 * 2 + 0] = m_s;
            mlS[((qs << 2) + kh) * 32 + l16 * 2 + 1] = l_s;
        }
        if (kh != 0) {
            const int idx6 = qs * 3 + (kh - 1);
            #pragma unroll
            for (int df = 0; df < 8; df++)
                #pragma unroll
                for (int r = 0; r < 4; r++)
                    scf[(idx6 * 16 + (lg << 2) + r) * 130 + (df << 4) + l16] = accO[df][r];
        }
        __syncthreads();
        if (kh == 0) {
            #pragma unroll
            for (int r = 0; r < 4; r++) {
                const int qoff = (lg << 2) + r;
                float m0v = mlS[(qs << 2) * 32 + qoff * 2],       l0v = mlS[(qs << 2) * 32 + qoff * 2 + 1];
                float m1v = mlS[((qs << 2) + 1) * 32 + qoff * 2], l1v = mlS[((qs << 2) + 1) * 32 + qoff * 2 + 1];
                float m2v = mlS[((qs << 2) + 2) * 32 + qoff * 2], l2v = mlS[((qs << 2) + 2) * 32 + qoff * 2 + 1];
                float m3v = mlS[((qs << 2) + 3) * 32 + qoff * 2], l3v = mlS[((qs << 2) + 3) * 32 + qoff * 2 + 1];
                float mst = fmaxf(fmaxf(m0v, m1v), fmaxf(m2v, m3v));
                float f0 = exp2fast(m0v - mst), f1 = exp2fast(m1v - mst);
                float f2 = exp2fast(m2v - mst), f3 = exp2fast(m3v - mst);
                float inv = 1.0f / (f0 * l0v + f1 * l1v + f2 * l2v + f3 * l3v);
                const int qrow = qrow0 + qoff;
                #pragma unroll
                for (int df = 0; df < 8; df++) {
                    float o = f0 * accO[df][r]
                            + f1 * scf[((qs * 3 + 0) * 16 + qoff) * 130 + (df << 4) + l16]
                            + f2 * scf[((qs * 3 + 1) * 16 + qoff) * 130 + (df << 4) + l16]
                            + f3 * scf[((qs * 3 + 2) * 16 + qoff) * 130 + (df << 4) + l16];
                    out[base + (size_t)qrow * D_ + (df << 4) + l16] = o * inv;
                }
            }
        }
        __syncthreads();   // scf reads done before next half overwrites Kl
    }
}

extern "C" void kernel_launch(void* const* d_in, const int* in_sizes, int n_in,
                              void* d_out, int out_size, void* d_ws, size_t ws_size,
                              hipStream_t stream) {
    (void)in_sizes; (void)n_in; (void)out_size; (void)ws_size;
    const float* x  = (const float*)d_in[0];
    const float* Wq = (const float*)d_in[1];
    const float* Wk = (const float*)d_in[2];
    const float* Wv = (const float*)d_in[3];

    unsigned short* qkv = (unsigned short*)d_ws;     // Q | K | Vp, bf16, 4MB each
    unsigned short* Wb  = (unsigned short*)d_out;    // temp bf16 W (overwritten by attn)

    wcvt<<<dim3(192), 256, 0, stream>>>(Wq, Wk, Wv, Wb);
    qkv_gemm<<<dim3(256), 512, 0, stream>>>(x, Wb, qkv);

    const unsigned short* Qw = qkv;
    const unsigned short* Kw = qkv + (size_t)B_ * T_ * D_;
    const unsigned short* Vw = qkv + 2 * (size_t)B_ * T_ * D_;
    attn_fwd<<<dim3(256), 512, 0, stream>>>(Qw, Kw, Vw, (float*)d_out);
}